// Round 1
// 594.088 us; speedup vs baseline: 1.5640x; 1.5640x over previous
//
#include <hip/hip_runtime.h>
#include <cstddef>

#define B_  8
#define C_  512
#define N_  16384
#define IC_ 64

#define K1_CHUNKS 2
#define K1_NSPLIT (N_ / (64 * K1_CHUNKS))   // 128 splits -> 1024 blocks

typedef float  f32x4  __attribute__((ext_vector_type(4)));
typedef float  f4     __attribute__((ext_vector_type(4)));
typedef short  bf16x8 __attribute__((ext_vector_type(8)));
typedef unsigned short us4 __attribute__((ext_vector_type(4)));

#define MFMA(a, b, c) __builtin_amdgcn_mfma_f32_16x16x32_bf16((a), (b), (c), 0, 0, 0)

// fp32 -> bf16 (truncate). Cheap (1 shift); bias is ~2^-9 rel, fine for the
// plain-bf16 (V/out) path.
__device__ __forceinline__ unsigned short tb(float f) {
    return (unsigned short)(__float_as_uint(f) >> 16);
}
// fp32 -> bf16 hi + bf16 lo (2-term split). hi = trunc(f); lo = trunc(f - hi).
// Dropped terms are O(2^-16) relative -> fp32-grade matmul via 3 MFMAs.
__device__ __forceinline__ void split2(float f, unsigned short &h, unsigned short &l) {
    unsigned u = __float_as_uint(f);
    h = (unsigned short)(u >> 16);
    float r = f - __uint_as_float(u & 0xffff0000u);
    l = (unsigned short)(__float_as_uint(r) >> 16);
}

// 4x4 outer-product accumulate (kept for the tiny fp32 mmix kernel)
#define FMA16(A, av, bv)                                                \
  A[0][0] += (av).x*(bv).x; A[0][1] += (av).x*(bv).y;                   \
  A[0][2] += (av).x*(bv).z; A[0][3] += (av).x*(bv).w;                   \
  A[1][0] += (av).y*(bv).x; A[1][1] += (av).y*(bv).y;                   \
  A[1][2] += (av).y*(bv).z; A[1][3] += (av).y*(bv).w;                   \
  A[2][0] += (av).z*(bv).x; A[2][1] += (av).z*(bv).y;                   \
  A[2][2] += (av).z*(bv).z; A[2][3] += (av).z*(bv).w;                   \
  A[3][0] += (av).w*(bv).x; A[3][1] += (av).w*(bv).y;                   \
  A[3][2] += (av).w*(bv).z; A[3][3] += (av).w*(bv).w;

// ---------------------------------------------------------------------------
// Kernel 1 (MFMA, split-bf16): fused Q,K projection + score partials.
// Per block: (b, nsplit), K1_CHUNKS chunks of 64 n each.
//   proj:  Q/K [64ic x 64n] = W[64x512] . X[512x64], hi/lo split (3 MFMAs/term)
//   score: S  += Q[64x64n] . K^T, hi/lo split, atomicAdd at end.
// Fragment reads use identical lane->k mapping for A and B (k-permutation
// invariant). D layout: col=lane&15, row=(lane>>4)*4+reg (HW-verified).
// ---------------------------------------------------------------------------
__global__ __launch_bounds__(256) void qk_scores_mfma(
    const float* __restrict__ x,
    const float* __restrict__ Wq, const float* __restrict__ bq,
    const float* __restrict__ Wk, const float* __restrict__ bk,
    float* __restrict__ S)
{
    __shared__ alignas(16) unsigned char lds_raw[55296];
    // staging planes, pitch 72 shorts (144 B = 9*16: b128-aligned rows, ~2-way banks)
    unsigned short (*XTh)[72] = (unsigned short(*)[72])(lds_raw +     0);
    unsigned short (*XTl)[72] = (unsigned short(*)[72])(lds_raw +  9216);
    unsigned short (*WQh)[72] = (unsigned short(*)[72])(lds_raw + 18432);
    unsigned short (*WQl)[72] = (unsigned short(*)[72])(lds_raw + 27648);
    unsigned short (*WKh)[72] = (unsigned short(*)[72])(lds_raw + 36864);
    unsigned short (*WKl)[72] = (unsigned short(*)[72])(lds_raw + 46080);
    // S-phase aliases (staging is dead after last proj k-step + barrier)
    unsigned short (*Qh)[72] = XTh;
    unsigned short (*Ql)[72] = XTl;
    unsigned short (*Kh)[72] = WQh;
    unsigned short (*Kl)[72] = WQl;

    const int bid  = blockIdx.x;
    const int nsp  = bid % K1_NSPLIT;
    const int b    = bid / K1_NSPLIT;
    const int tid  = threadIdx.x;
    const int lane = tid & 63;
    const int wv   = tid >> 6;      // wave 0..3 -> owns ic strip 16*wv
    const int lr   = lane & 15;     // frag row/col selector
    const int lg   = lane >> 4;     // frag k-group

    // staging thread coords
    const int wrow = tid >> 2;            // W row 0..63
    const int wc0  = (tid & 3) * 16;      // W col base
    const int xcg  = tid >> 4;            // x c-group (4 rows)
    const int xng  = tid & 15;            // x n-group (4 cols)

    f32x4 Sacc[4] = {};  // S tiles (i-strip 16*wv) x (jt 0..3)

    for (int ch = 0; ch < K1_CHUNKS; ++ch) {
        const int n0 = (nsp * K1_CHUNKS + ch) * 64;
        f32x4 Qacc[4] = {};
        f32x4 Kacc[4] = {};

        for (int kc = 0; kc < C_; kc += 64) {
            // issue x loads first (hide HBM latency under the W cvt work)
            f4 xr[4];
            #pragma unroll
            for (int r = 0; r < 4; ++r)
                xr[r] = *(const f4*)&x[((size_t)(b * C_ + kc + 4 * xcg + r)) * N_ + n0 + 4 * xng];

            // stage Wq/Wk hi/lo [64ic][64c]
            {
                const float* gq = &Wq[wrow * C_ + kc + wc0];
                const float* gk = &Wk[wrow * C_ + kc + wc0];
                #pragma unroll
                for (int v = 0; v < 4; ++v) {
                    f4 q4 = *(const f4*)(gq + 4 * v);
                    f4 k4 = *(const f4*)(gk + 4 * v);
                    us4 qh, ql2, kh, kl2;
                    #pragma unroll
                    for (int e = 0; e < 4; ++e) {
                        unsigned short h, l;
                        split2(q4[e], h, l); qh[e] = h; ql2[e] = l;
                        split2(k4[e], h, l); kh[e] = h; kl2[e] = l;
                    }
                    *(us4*)&WQh[wrow][wc0 + 4 * v] = qh;
                    *(us4*)&WQl[wrow][wc0 + 4 * v] = ql2;
                    *(us4*)&WKh[wrow][wc0 + 4 * v] = kh;
                    *(us4*)&WKl[wrow][wc0 + 4 * v] = kl2;
                }
            }
            // stage X^T hi/lo [64n][64c] via 4x4 register transpose
            #pragma unroll
            for (int nn = 0; nn < 4; ++nn) {
                us4 hv, lv;
                #pragma unroll
                for (int r = 0; r < 4; ++r) {
                    unsigned short h, l;
                    split2(xr[r][nn], h, l);
                    hv[r] = h; lv[r] = l;
                }
                *(us4*)&XTh[4 * xng + nn][4 * xcg] = hv;
                *(us4*)&XTl[4 * xng + nn][4 * xcg] = lv;
            }
            __syncthreads();

            #pragma unroll
            for (int ks = 0; ks < 2; ++ks) {
                const int c8 = ks * 32 + lg * 8;
                bf16x8 aqh = *(const bf16x8*)&WQh[16 * wv + lr][c8];
                bf16x8 aql = *(const bf16x8*)&WQl[16 * wv + lr][c8];
                bf16x8 akh = *(const bf16x8*)&WKh[16 * wv + lr][c8];
                bf16x8 akl = *(const bf16x8*)&WKl[16 * wv + lr][c8];
                #pragma unroll
                for (int nt = 0; nt < 4; ++nt) {
                    bf16x8 xh = *(const bf16x8*)&XTh[16 * nt + lr][c8];
                    bf16x8 xl = *(const bf16x8*)&XTl[16 * nt + lr][c8];
                    Qacc[nt] = MFMA(aqh, xh, Qacc[nt]);
                    Qacc[nt] = MFMA(aqh, xl, Qacc[nt]);
                    Qacc[nt] = MFMA(aql, xh, Qacc[nt]);
                    Kacc[nt] = MFMA(akh, xh, Kacc[nt]);
                    Kacc[nt] = MFMA(akh, xl, Kacc[nt]);
                    Kacc[nt] = MFMA(akl, xh, Kacc[nt]);
                }
            }
            __syncthreads();
        }

        // bias + re-split Q,K to bf16 hi/lo in LDS (aliased over staging)
        float bqr[4], bkr[4];
        #pragma unroll
        for (int r = 0; r < 4; ++r) {
            bqr[r] = bq[16 * wv + 4 * lg + r];
            bkr[r] = bk[16 * wv + 4 * lg + r];
        }
        #pragma unroll
        for (int nt = 0; nt < 4; ++nt) {
            #pragma unroll
            for (int r = 0; r < 4; ++r) {
                const int i = 16 * wv + 4 * lg + r;   // D row
                const int n = 16 * nt + lr;           // D col
                unsigned short h, l;
                split2(Qacc[nt][r] + bqr[r], h, l); Qh[i][n] = h; Ql[i][n] = l;
                split2(Kacc[nt][r] + bkr[r], h, l); Kh[i][n] = h; Kl[i][n] = l;
            }
        }
        __syncthreads();

        // S += Q . K^T over this chunk's 64 n (k-dim = n)
        #pragma unroll
        for (int ks = 0; ks < 2; ++ks) {
            const int nn0 = ks * 32 + lg * 8;
            bf16x8 qh = *(const bf16x8*)&Qh[16 * wv + lr][nn0];
            bf16x8 ql = *(const bf16x8*)&Ql[16 * wv + lr][nn0];
            #pragma unroll
            for (int jt = 0; jt < 4; ++jt) {
                bf16x8 kh = *(const bf16x8*)&Kh[16 * jt + lr][nn0];
                bf16x8 kl = *(const bf16x8*)&Kl[16 * jt + lr][nn0];
                Sacc[jt] = MFMA(qh, kh, Sacc[jt]);
                Sacc[jt] = MFMA(qh, kl, Sacc[jt]);
                Sacc[jt] = MFMA(ql, kh, Sacc[jt]);
            }
        }
        __syncthreads();   // before next chunk overwrites the aliased staging
    }

    #pragma unroll
    for (int jt = 0; jt < 4; ++jt) {
        #pragma unroll
        for (int r = 0; r < 4; ++r) {
            const int i = 16 * wv + 4 * lg + r;
            const int j = 16 * jt + lr;
            atomicAdd(&S[(b * IC_ + i) * IC_ + j], Sacc[jt][r]);
        }
    }
}

// ---------------------------------------------------------------------------
// Kernel 2: softmax over axis=1 (over i, per (b,j) column), in place. (fp32)
// ---------------------------------------------------------------------------
__global__ void softmax_kernel(float* __restrict__ S)
{
    int t = blockIdx.x * blockDim.x + threadIdx.x;
    if (t >= B_ * IC_) return;
    int b = t >> 6, j = t & 63;
    float m = -1e30f;
    for (int i = 0; i < IC_; ++i)
        m = fmaxf(m, S[(b * IC_ + i) * IC_ + j]);
    float s = 0.f;
    for (int i = 0; i < IC_; ++i)
        s += expf(S[(b * IC_ + i) * IC_ + j] - m);
    float inv = 1.0f / s;
    for (int i = 0; i < IC_; ++i)
        S[(b * IC_ + i) * IC_ + j] = expf(S[(b * IC_ + i) * IC_ + j] - m) * inv;
}

// ---------------------------------------------------------------------------
// Kernel 3: M[b,c,j] = sum_o Wr[c,o] * w[b,o,j]  (tiny fp32 GEMM, unchanged)
// ---------------------------------------------------------------------------
__global__ __launch_bounds__(256) void mmix_kernel(
    const float* __restrict__ Wr, const float* __restrict__ S,
    float* __restrict__ M)
{
    const int bid   = blockIdx.x;
    const int ctile = bid % 8;
    const int b     = bid / 8;

    __shared__ float Wrt[64][68];
    __shared__ float wt[64][68];

    const int tid = threadIdx.x;
    const int tx  = tid & 15;
    const int ty  = tid >> 4;

    #pragma unroll
    for (int r = 0; r < 16; ++r) {
        int idx = r * 256 + tid;
        int cp = idx >> 6, o = idx & 63;
        Wrt[o][cp] = Wr[(ctile * 64 + cp) * IC_ + o];
    }
    #pragma unroll
    for (int r = 0; r < 16; ++r) {
        int idx = r * 256 + tid;
        int o = idx >> 6, j = idx & 63;
        wt[o][j] = S[(b * IC_ + o) * IC_ + j];
    }
    __syncthreads();

    float acc[4][4] = {};
    #pragma unroll
    for (int o = 0; o < 64; ++o) {
        float4 av = *(const float4*)&Wrt[o][ty * 4];
        float4 bv4 = *(const float4*)&wt[o][tx * 4];
        FMA16(acc, av, bv4);
    }

    #pragma unroll
    for (int i = 0; i < 4; ++i) {
        float4 o4;
        o4.x = acc[i][0]; o4.y = acc[i][1]; o4.z = acc[i][2]; o4.w = acc[i][3];
        *(float4*)&M[((size_t)(b * C_ + ctile * 64 + ty * 4 + i)) * IC_ + tx * 4] = o4;
    }
}

// ---------------------------------------------------------------------------
// Kernel 4 (MFMA, plain bf16): fused V projection + out GEMM + bias + residual.
// Phase 1: V[64ic x 64n] = Wv.X (bf16 MFMA), parked transposed in LDS (V^T[n][j]).
// Phase 2: per c-tile, out = M[64c x 64j].V + br + x (residual in fp32, exact).
// ---------------------------------------------------------------------------
__global__ __launch_bounds__(256) void vout_mfma(
    const float* __restrict__ x,
    const float* __restrict__ Wv, const float* __restrict__ bv,
    const float* __restrict__ M,  const float* __restrict__ br,
    float* __restrict__ out)
{
    __shared__ alignas(16) unsigned char lds_raw[36864];
    unsigned short (*XTh)[72] = (unsigned short(*)[72])(lds_raw +     0);
    unsigned short (*WVh)[72] = (unsigned short(*)[72])(lds_raw +  9216);
    unsigned short (*VT )[72] = (unsigned short(*)[72])(lds_raw + 18432);
    unsigned short (*Mt )[72] = (unsigned short(*)[72])(lds_raw + 27648);

    const int bid   = blockIdx.x;
    const int ntile = bid % (N_ / 64);
    const int b     = bid / (N_ / 64);
    const int n0    = ntile * 64;

    const int tid  = threadIdx.x;
    const int lane = tid & 63;
    const int wv   = tid >> 6;
    const int lr   = lane & 15;
    const int lg   = lane >> 4;

    const int wrow = tid >> 2;
    const int wc0  = (tid & 3) * 16;
    const int xcg  = tid >> 4;
    const int xng  = tid & 15;

    // ---- Phase 1: V tile ----
    f32x4 Vacc[4] = {};
    for (int kc = 0; kc < C_; kc += 64) {
        f4 xr[4];
        #pragma unroll
        for (int r = 0; r < 4; ++r)
            xr[r] = *(const f4*)&x[((size_t)(b * C_ + kc + 4 * xcg + r)) * N_ + n0 + 4 * xng];

        {
            const float* gv = &Wv[wrow * C_ + kc + wc0];
            #pragma unroll
            for (int v = 0; v < 4; ++v) {
                f4 w4 = *(const f4*)(gv + 4 * v);
                us4 hv;
                #pragma unroll
                for (int e = 0; e < 4; ++e) hv[e] = tb(w4[e]);
                *(us4*)&WVh[wrow][wc0 + 4 * v] = hv;
            }
        }
        #pragma unroll
        for (int nn = 0; nn < 4; ++nn) {
            us4 hv;
            #pragma unroll
            for (int r = 0; r < 4; ++r) hv[r] = tb(xr[r][nn]);
            *(us4*)&XTh[4 * xng + nn][4 * xcg] = hv;
        }
        __syncthreads();

        #pragma unroll
        for (int ks = 0; ks < 2; ++ks) {
            const int c8 = ks * 32 + lg * 8;
            bf16x8 av = *(const bf16x8*)&WVh[16 * wv + lr][c8];
            #pragma unroll
            for (int nt = 0; nt < 4; ++nt) {
                bf16x8 xb = *(const bf16x8*)&XTh[16 * nt + lr][c8];
                Vacc[nt] = MFMA(av, xb, Vacc[nt]);
            }
        }
        __syncthreads();
    }

    // bias + park V^T[n][j] as bf16 (lane holds 4 consecutive ic for one n)
    float bvr[4];
    #pragma unroll
    for (int r = 0; r < 4; ++r) bvr[r] = bv[16 * wv + 4 * lg + r];
    #pragma unroll
    for (int nt = 0; nt < 4; ++nt) {
        us4 hv;
        #pragma unroll
        for (int r = 0; r < 4; ++r) hv[r] = tb(Vacc[nt][r] + bvr[r]);
        *(us4*)&VT[16 * nt + lr][16 * wv + 4 * lg] = hv;
    }
    __syncthreads();

    // ---- Phase 2: out over 8 c-tiles ----
    for (int ctile = 0; ctile < 8; ++ctile) {
        {
            const float* gm = &M[((size_t)(b * C_ + ctile * 64 + wrow)) * IC_ + wc0];
            #pragma unroll
            for (int v = 0; v < 4; ++v) {
                f4 m4 = *(const f4*)(gm + 4 * v);
                us4 hv;
                #pragma unroll
                for (int e = 0; e < 4; ++e) hv[e] = tb(m4[e]);
                *(us4*)&Mt[wrow][wc0 + 4 * v] = hv;
            }
        }
        __syncthreads();

        f32x4 Oacc[4] = {};
        #pragma unroll
        for (int ks = 0; ks < 2; ++ks) {
            const int j8 = ks * 32 + lg * 8;
            bf16x8 am = *(const bf16x8*)&Mt[16 * wv + lr][j8];
            #pragma unroll
            for (int nt = 0; nt < 4; ++nt) {
                bf16x8 vb = *(const bf16x8*)&VT[16 * nt + lr][j8];
                Oacc[nt] = MFMA(am, vb, Oacc[nt]);
            }
        }

        float brr[4];
        #pragma unroll
        for (int r = 0; r < 4; ++r) brr[r] = br[ctile * 64 + 16 * wv + 4 * lg + r];

        #pragma unroll
        for (int nt = 0; nt < 4; ++nt) {
            #pragma unroll
            for (int r = 0; r < 4; ++r) {
                const int c = ctile * 64 + 16 * wv + 4 * lg + r;
                const int n = n0 + 16 * nt + lr;
                const size_t idx = ((size_t)(b * C_ + c)) * N_ + n;
                out[idx] = Oacc[nt][r] + brr[r] + x[idx];
            }
        }
        __syncthreads();   // before next ctile restages Mt
    }
}

// ---------------------------------------------------------------------------
extern "C" void kernel_launch(void* const* d_in, const int* in_sizes, int n_in,
                              void* d_out, int out_size, void* d_ws, size_t ws_size,
                              hipStream_t stream)
{
    const float* x  = (const float*)d_in[0];
    const float* Wq = (const float*)d_in[1];
    const float* bq = (const float*)d_in[2];
    const float* Wk = (const float*)d_in[3];
    const float* bk = (const float*)d_in[4];
    const float* Wv = (const float*)d_in[5];
    const float* bv = (const float*)d_in[6];
    const float* Wr = (const float*)d_in[7];
    const float* br = (const float*)d_in[8];
    float* out = (float*)d_out;

    // Workspace: S (scores->weights) 128 KB + M (Wr.w) 1 MB.
    float* S = (float*)d_ws;
    float* M = S + (size_t)B_ * IC_ * IC_;

    hipMemsetAsync(S, 0, (size_t)B_ * IC_ * IC_ * sizeof(float), stream);

    qk_scores_mfma<<<B_ * K1_NSPLIT, 256, 0, stream>>>(x, Wq, bq, Wk, bk, S);
    softmax_kernel<<<2,              256, 0, stream>>>(S);
    mmix_kernel   <<<B_ * 8,         256, 0, stream>>>(Wr, S, M);
    vout_mfma     <<<B_ * (N_ / 64), 256, 0, stream>>>(x, Wv, bv, M, br, out);
}